// Round 10
// baseline (2440.750 us; speedup 1.0000x reference)
//
#include <hip/hip_runtime.h>

// ---------------------------------------------------------------------------
// Persistent fused LSTM for MI355X (gfx950).  Round 10 submission
// (= Round-7/8/9 kernel, unchanged; R7-R9 never ran — GPU acquisition
// timeouts. Three audit passes clean. No new evidence => no mutation.)
//
// R2: __threadfence (wbl2) writeback-bound, 8652 us. R6: relaxed agent-scope
// atomics for h+flags -> 2393 us (passed, absmax 0.0039). Now latency/sync
// bound at 9.2 us/step (MfmaUtil 5%, hbm 1%). This round removes serial
// phase overhead, keeping the PROVEN sync protocol byte-identical:
//  - SWAPPED-OPERAND MFMA: mfma(w_frag, h_frag) gives D^T, so each wn==0
//    thread holds 4 consecutive h-cols of one row -> h stored directly from
//    registers as ONE 8B agent atomic per m-frag. hstage LDS + one barrier
//    deleted (5 -> 4 barriers/step).
//  - zlds pitch 16 -> 20 floats: old 64B pitch put all lanes on banks
//    {0,16} (16-way conflict, 9.1e7 conflict cycles); 80B pitch tiles all
//    32 banks at free 2-way.
//
// Decomposition: 256 blocks = 8 batch-groups (blockIdx&7) x 32 col-blocks.
// Block owns 64 batch rows x 16 h-cols. Weights (4 gates, fp16, [n][k])
// LDS-resident all 256 steps. x-proj + bias folded via K-augmentation
// (K = 512 h + 10 xe + 1 bias + pad = 17 k-steps of 32). Cell state c in
// fp32 registers. h exchange: ping-pong fp16 buffers in d_ws, relaxed
// AGENT-scope 64-bit atomics (coherent at fabric/LLC); ordering = producer
// vmcnt(0) drain + barrier, then tid0 flag store; consumer spins on 32
// write-once MAGIC flags (ws poison 0xAA != MAGIC -> no init/reset race).
// ---------------------------------------------------------------------------

#define BATCH  512
#define TSTEPS 256
#define HDIM   512
#define EDIM   10
#define NCLS   10

#define GROUPS 8
#define CBLK   32     // column blocks per group
#define MBLK   64     // batch rows per group
#define NBLK   64     // gate-cols per block = 4 gates * 16 hcols
#define PITCH  552    // LDS row pitch (halfs): 1104B
#define ZP     20     // zlds row pitch (floats): 80B -> all 32 banks, 2-way
#define MAGICF 0x13572468u

typedef _Float16 half_t;
typedef _Float16 f16x8 __attribute__((ext_vector_type(8)));
typedef float    f32x4 __attribute__((ext_vector_type(4)));
typedef unsigned long long ull_t;

__device__ __forceinline__ float sigm_f(float x) {
    return 1.f / (1.f + __expf(-x));
}
__device__ __forceinline__ float tanh_f(float x) {
    x = fminf(fmaxf(x, -15.f), 15.f);   // avoid inf/inf
    float e = __expf(2.f * x);
    return (e - 1.f) / (e + 1.f);
}

// Spin until all 32 column-blocks of this group set their MAGIC slot for a
// step. Relaxed agent loads bypass stale caches; subsequent h reads are
// themselves agent-coherent atomics. Compiler fence stops any hoisting.
__device__ __forceinline__ void group_wait(const unsigned int* fl, int wave, int lane) {
    if (wave == 0) {
        for (;;) {
            unsigned int v = MAGICF;
            if (lane < 32)
                v = __hip_atomic_load(fl + lane, __ATOMIC_RELAXED, __HIP_MEMORY_SCOPE_AGENT);
            if (__all(v == MAGICF)) break;
            __builtin_amdgcn_s_sleep(1);
        }
    }
    asm volatile("" ::: "memory");
    __syncthreads();
}

__global__ __launch_bounds__(256, 1) void lstm_persist(
    const int* __restrict__ x, const float* __restrict__ emb,
    const float* __restrict__ Wgx, const float* __restrict__ Wgh, const float* __restrict__ bg,
    const float* __restrict__ Wix, const float* __restrict__ Wih, const float* __restrict__ bi,
    const float* __restrict__ Wfx, const float* __restrict__ Wfh, const float* __restrict__ bf,
    const float* __restrict__ Wox, const float* __restrict__ Woh, const float* __restrict__ bo,
    const float* __restrict__ Wph, const float* __restrict__ bp,
    float* __restrict__ out, half_t* __restrict__ h0buf, half_t* __restrict__ h1buf,
    unsigned int* __restrict__ flags)
{
    __shared__ half_t Alds[MBLK * PITCH];    // h tile + xe augmentation (70656 B)
    __shared__ half_t Blds[NBLK * PITCH];    // W^T slice: [n][k]         (70656 B)
    __shared__ float  zlds[2 * 64 * ZP];     // gate z exchange           (10240 B)

    const int tid  = threadIdx.x;
    const int wave = tid >> 6, lane = tid & 63;
    const int wm   = wave >> 1, wn = wave & 1;      // 2x2 wave grid over 64x64 tile
    const int g    = blockIdx.x & 7;                // batch group (XCD-aligned)
    const int j    = blockIdx.x >> 3;               // column block 0..31

    // ---- one-time init: weights^T -> LDS (fp16), zero pads ----
    #pragma unroll
    for (int gate = 0; gate < 4; ++gate) {
        const float* W = (gate == 0) ? Wgh : (gate == 1) ? Wih : (gate == 2) ? Wfh : Woh;
        for (int idx = tid; idx < HDIM * 16; idx += 256) {
            int c = idx & 15, k = idx >> 4;       // coalesced 64B global reads
            Blds[(gate * 16 + c) * PITCH + k] = (half_t)W[k * HDIM + j * 16 + c];
        }
    }
    if (tid < NBLK) {
        int gate = tid >> 4, c = tid & 15, hcol = j * 16 + c;
        const float* Wx = (gate == 0) ? Wgx : (gate == 1) ? Wix : (gate == 2) ? Wfx : Wox;
        const float* bb = (gate == 0) ? bg  : (gate == 1) ? bi  : (gate == 2) ? bf  : bo;
        #pragma unroll
        for (int e = 0; e < EDIM; ++e)
            Blds[tid * PITCH + 512 + e] = (half_t)Wx[e * HDIM + hcol];
        Blds[tid * PITCH + 522] = (half_t)bb[hcol];    // bias row (A has 1.0 there)
        for (int k = 523; k < PITCH; ++k) Blds[tid * PITCH + k] = (half_t)0.f;
    }
    if (tid < MBLK) {
        for (int k = 523; k < PITCH; ++k) Alds[tid * PITCH + k] = (half_t)0.f;
    }

    float c_state[8];
    #pragma unroll
    for (int i = 0; i < 8; ++i) c_state[i] = 0.f;

    for (int t = 0; t < TSTEPS; ++t) {
        // xe staging (x/emb immutable inputs, plain cached loads)
        if (tid < MBLK) {
            int m = tid;
            int idx = x[(g * MBLK + m) * TSTEPS + t];
            const float* er = emb + idx * EDIM;
            #pragma unroll
            for (int e = 0; e < EDIM; ++e)
                Alds[m * PITCH + 512 + e] = (half_t)er[e];
            Alds[m * PITCH + 522] = (half_t)1.f;
        }
        if (t > 0) {
            group_wait(flags + (g * TSTEPS + (t - 1)) * 32, wave, lane);
            // stage h_t: coherent (agent) 8B loads from LLC ping-pong -> LDS
            const ull_t* hsrc = (const ull_t*)(((t & 1) ? h1buf : h0buf)
                                               + (size_t)g * MBLK * HDIM);
            #pragma unroll
            for (int i = 0; i < 16; ++i) {
                int m = wave * 16 + i;
                ull_t v0 = __hip_atomic_load(hsrc + m * 128 + lane * 2,
                                             __ATOMIC_RELAXED, __HIP_MEMORY_SCOPE_AGENT);
                ull_t v1 = __hip_atomic_load(hsrc + m * 128 + lane * 2 + 1,
                                             __ATOMIC_RELAXED, __HIP_MEMORY_SCOPE_AGENT);
                ull_t* dst = (ull_t*)&Alds[m * PITCH + lane * 8];
                dst[0] = v0; dst[1] = v1;
            }
        }
        __syncthreads();

        // ---- GEMM 64x64xK, SWAPPED operands: D^T = (W-rows) x (h-rows) ----
        // acc[nf][mf]: row = gate-col hc = (lane>>4)*4+reg, col = m = lane&15.
        // Wave (wm,wn): gates {2wn, 2wn+1}, m in [wm*32, wm*32+32).
        f32x4 acc00 = {0.f, 0.f, 0.f, 0.f};   // gate 2wn+0, m-frag 0
        f32x4 acc01 = {0.f, 0.f, 0.f, 0.f};   // gate 2wn+0, m-frag 1
        f32x4 acc10 = {0.f, 0.f, 0.f, 0.f};   // gate 2wn+1, m-frag 0
        f32x4 acc11 = {0.f, 0.f, 0.f, 0.f};   // gate 2wn+1, m-frag 1
        const int row = lane & 15, kq = lane >> 4;
        for (int ks = (t == 0) ? 16 : 0; ks <= 16; ++ks) {   // t=0: h==0, x+bias only
            int ko = ks * 32 + kq * 8;
            f16x8 h0v = *(const f16x8*)&Alds[(wm * 32 +      row) * PITCH + ko];
            f16x8 h1v = *(const f16x8*)&Alds[(wm * 32 + 16 + row) * PITCH + ko];
            f16x8 w0  = *(const f16x8*)&Blds[(wn * 32 +      row) * PITCH + ko];
            f16x8 w1  = *(const f16x8*)&Blds[(wn * 32 + 16 + row) * PITCH + ko];
            acc00 = __builtin_amdgcn_mfma_f32_16x16x32_f16(w0, h0v, acc00, 0, 0, 0);
            acc01 = __builtin_amdgcn_mfma_f32_16x16x32_f16(w0, h1v, acc01, 0, 0, 0);
            acc10 = __builtin_amdgcn_mfma_f32_16x16x32_f16(w1, h0v, acc10, 0, 0, 0);
            acc11 = __builtin_amdgcn_mfma_f32_16x16x32_f16(w1, h1v, acc11, 0, 0, 0);
        }

        // waves wn==1 hold gates f,o -> push z through LDS to partner lane
        if (wn == 1) {
            float* zp = zlds + (wm * 64 + lane) * ZP;
            *(f32x4*)(zp + 0)  = acc00;    // f, m-frag 0
            *(f32x4*)(zp + 4)  = acc10;    // o, m-frag 0
            *(f32x4*)(zp + 8)  = acc01;    // f, m-frag 1
            *(f32x4*)(zp + 12) = acc11;    // o, m-frag 1
        }
        __syncthreads();

        // waves wn==0: activations + cell update -> DIRECT 8B coherent store
        // (thread holds 4 consecutive h-cols of row m -> contiguous 8B)
        if (wn == 0) {
            const float* zp = zlds + (wm * 64 + lane) * ZP;
            ull_t* hd = (ull_t*)((t & 1) ? h0buf : h1buf);   // step t -> buffer (t+1)&1
            #pragma unroll
            for (int mf = 0; mf < 2; ++mf) {
                f32x4 zgv = mf ? acc01 : acc00;        // gate 0 (g)
                f32x4 ziv = mf ? acc11 : acc10;        // gate 1 (i)
                union { ull_t u; half_t h[4]; } pack;
                #pragma unroll
                for (int r = 0; r < 4; ++r) {
                    float zg = zgv[r], zi = ziv[r];
                    float zf = zp[mf * 8 + r];         // gate 2 (f)
                    float zo = zp[mf * 8 + 4 + r];     // gate 3 (o)
                    float gv = tanh_f(zg), iv = sigm_f(zi);
                    float fv = sigm_f(zf), ov = sigm_f(zo);
                    int ci = mf * 4 + r;
                    float cv = gv * iv + c_state[ci] * fv;
                    c_state[ci] = cv;
                    pack.h[r] = (half_t)(tanh_f(cv) * ov);
                }
                int m = wm * 32 + mf * 16 + (lane & 15);
                __hip_atomic_store(hd + (size_t)(g * MBLK + m) * 128 + j * 4 + (lane >> 4),
                                   pack.u, __ATOMIC_RELAXED, __HIP_MEMORY_SCOPE_AGENT);
            }
            asm volatile("s_waitcnt vmcnt(0)" ::: "memory");  // h at LLC before barrier
        }
        __syncthreads();
        if (tid == 0)
            __hip_atomic_store(flags + (g * TSTEPS + t) * 32 + j, MAGICF,
                               __ATOMIC_RELAXED, __HIP_MEMORY_SCOPE_AGENT);
    }

    // ---- epilogue: out = h_T @ Wph + bp; block handles rows 64g+2j, +1 ----
    group_wait(flags + (g * TSTEPS + (TSTEPS - 1)) * 32, wave, lane);
    if (wave == 0) {
        const ull_t* hT = (const ull_t*)h0buf;     // step 255 (odd) wrote buffer 0
        int rb0 = g * MBLK + j * 2;
        union { ull_t u; half_t h[4]; } p0, p1;
        #pragma unroll
        for (int i = 0; i < 2; ++i) {
            p0.u = __hip_atomic_load(hT + (size_t)(rb0 + i) * 128 + lane * 2,
                                     __ATOMIC_RELAXED, __HIP_MEMORY_SCOPE_AGENT);
            p1.u = __hip_atomic_load(hT + (size_t)(rb0 + i) * 128 + lane * 2 + 1,
                                     __ATOMIC_RELAXED, __HIP_MEMORY_SCOPE_AGENT);
            float hreg[8];
            #pragma unroll
            for (int kk = 0; kk < 4; ++kk) { hreg[kk] = (float)p0.h[kk]; hreg[4 + kk] = (float)p1.h[kk]; }
            for (int cc = 0; cc < NCLS; ++cc) {
                float s = 0.f;
                #pragma unroll
                for (int kk = 0; kk < 8; ++kk)
                    s += hreg[kk] * Wph[(lane * 8 + kk) * NCLS + cc];
                #pragma unroll
                for (int off = 32; off > 0; off >>= 1) s += __shfl_down(s, off);
                if (lane == 0) out[(rb0 + i) * NCLS + cc] = s + bp[cc];
            }
        }
    }
}

extern "C" void kernel_launch(void* const* d_in, const int* in_sizes, int n_in,
                              void* d_out, int out_size, void* d_ws, size_t ws_size,
                              hipStream_t stream) {
    (void)in_sizes; (void)n_in; (void)out_size; (void)ws_size;
    const int*   x   = (const int*)d_in[0];
    const float* emb = (const float*)d_in[1];
    const float* Wgx = (const float*)d_in[2];
    const float* Wgh = (const float*)d_in[3];
    const float* bg  = (const float*)d_in[4];
    const float* Wix = (const float*)d_in[5];
    const float* Wih = (const float*)d_in[6];
    const float* bi  = (const float*)d_in[7];
    const float* Wfx = (const float*)d_in[8];
    const float* Wfh = (const float*)d_in[9];
    const float* bf  = (const float*)d_in[10];
    const float* Wox = (const float*)d_in[11];
    const float* Woh = (const float*)d_in[12];
    const float* bo  = (const float*)d_in[13];
    const float* Wph = (const float*)d_in[14];
    const float* bp  = (const float*)d_in[15];
    float* out = (float*)d_out;

    // ws layout: h ping-pong (2 x 512x512 fp16 = 1 MB) + flags (256 KB)
    half_t* h0 = (half_t*)d_ws;
    half_t* h1 = h0 + BATCH * HDIM;
    unsigned int* flags = (unsigned int*)((char*)d_ws + 2 * BATCH * HDIM * sizeof(half_t));

    void* args[] = { &x, &emb, &Wgx, &Wgh, &bg, &Wix, &Wih, &bi, &Wfx, &Wfh, &bf,
                     &Wox, &Woh, &bo, &Wph, &bp, &out, &h0, &h1, &flags };
    hipLaunchCooperativeKernel(reinterpret_cast<const void*>(lstm_persist),
                               dim3(GROUPS * CBLK), dim3(256), args, 0u, stream);
}